// Round 2
// baseline (237.028 us; speedup 1.0000x reference)
//
#include <hip/hip_runtime.h>
#include <hip/hip_bf16.h>

// GCNConv: out = D * (A @ (D * (X@W))) + bias,  D = rsqrt(rowsum(A)+1)
// N=100000, E=640000, C=128.
// R2: CSR gather replaced atomic scatter (1285->317us).
// R3: bf16 MFMA GEMM (317->301us).
// R4: 1 atomic/edge CSR build, packed uint2 edges, bf16 Y (301->242us).
// R5: MLP unrolls in rank/place/gather (242->230us).
// R6: gemm LDS-staged Wt (latency-bound on global re-fetch), 216us.
// R7: resubmit (infra fail), 215us. Profile: no user dispatch >41us ->
//     wall is launch-count-bound (~10 launches x ~8-10us gap/overhead).
// R8 (this round): fuse 11 launches -> 6. wcvt rides in rank dispatch;
//     scan2 folded into scan3 (per-block bsum reduce); dinv folded into
//     scan3 via float deg atomics in rank; place rides in gemm dispatch.
//     Inner loops of gemm/gather byte-identical to R6.

#define N_CH 128
#define WT_LD 136  // padded LDS row stride (ushorts): banks (4m+4q)%32 -> 2-way max

typedef __attribute__((ext_vector_type(8))) short short8;
typedef __attribute__((ext_vector_type(4))) float f32x4;
typedef __attribute__((ext_vector_type(4))) unsigned short ushort4v;

__device__ inline unsigned short f2bf(float f) {
    unsigned u = __float_as_uint(f);
    return (unsigned short)((u + 0x7FFFu + ((u >> 16) & 1u)) >> 16);  // RNE
}
__device__ inline float bf2f(unsigned short h) {
    return __uint_as_float(((unsigned)h) << 16);
}

// ---- rank[e] = atomicAdd(&cnt[row[e]], 1); deg[row] += val; + wcvt ------
// Blocks [0, rankBlocks): 8 edges/thread. Blocks [rankBlocks, +64): W cvt.
__global__ __launch_bounds__(256) void rank_kernel(const int* __restrict__ row,
                                                   const float* __restrict__ vals,
                                                   int* __restrict__ cnt,
                                                   float* __restrict__ deg,
                                                   int* __restrict__ rank,
                                                   const float* __restrict__ W,
                                                   unsigned short* __restrict__ Wt,
                                                   int E, int rankBlocks) {
    if ((int)blockIdx.x >= rankBlocks) {
        // W convert+transpose: Wt[n][k] = bf16(W[k][n]); 16384 elements
        int i = (blockIdx.x - rankBlocks) * 256 + threadIdx.x;
        int k = i >> 7, n = i & 127;
        Wt[n * N_CH + k] = f2bf(W[k * N_CH + n]);
        return;
    }
    int e0 = blockIdx.x * 2048 + threadIdx.x;
#pragma unroll
    for (int j = 0; j < 8; ++j) {
        int e = e0 + j * 256;
        if (e < E) {
            int r = row[e];
            rank[e] = atomicAdd(&cnt[r], 1);
            atomicAdd(&deg[r], vals[e]);
        }
    }
}

// ---- block-local exclusive scan of cnt -> pos; block sums -> bsum --------
__global__ __launch_bounds__(256) void scan1_kernel(const int* __restrict__ cnt,
                                                    int* __restrict__ pos,
                                                    int* __restrict__ bsum, int N) {
    __shared__ int s[256];
    int t = threadIdx.x;
    int i = blockIdx.x * 256 + t;
    int v = (i < N) ? cnt[i] : 0;
    s[t] = v;
    __syncthreads();
    for (int off = 1; off < 256; off <<= 1) {
        int x = (t >= off) ? s[t - off] : 0;
        __syncthreads();
        s[t] += x;
        __syncthreads();
    }
    if (i < N) pos[i] = s[t] - v;
    if (t == 255) bsum[blockIdx.x] = s[t];
}

// ---- pos[i] += sum(bsum[0..blk-1]); dinv[i] = rsqrt(deg[i]+1) ------------
// Each block reduces its own bsum prefix (<=391 ints, L2-broadcast).
__global__ __launch_bounds__(256) void scan3_kernel(int* __restrict__ pos,
                                                    const int* __restrict__ bsum,
                                                    const float* __restrict__ deg,
                                                    float* __restrict__ dinv, int N) {
    __shared__ int s[256];
    int t = threadIdx.x;
    int b = blockIdx.x;
    int acc = 0;
    for (int j = t; j < b; j += 256) acc += bsum[j];
    s[t] = acc;
    __syncthreads();
    for (int off = 128; off > 0; off >>= 1) {
        if (t < off) s[t] += s[t + off];
        __syncthreads();
    }
    int i = b * 256 + t;
    if (i < N) {
        pos[i] += s[0];
        dinv[i] = rsqrtf(deg[i] + 1.0f);
    }
}

// ---- fused dispatch: gemm blocks [0,gemmBlocks) + place blocks after -----
// gemm: Ybf[n,:] = bf16( dinv[n] * (X[n,:] @ W) ), bf16 MFMA.
//   Block = 4 waves, 128 rows. Wt staged in LDS (padded stride -> no bank
//   conflicts); each wave does 2 16-row tiles. C/D: col=lane&15,
//   row=(lane>>4)*4+reg.
// place: epack[pos[r]+rank[e]] = {col,val}; 4 edges/thread, no atomics.
__global__ __launch_bounds__(256) void gemm_place_kernel(
        const float* __restrict__ X, const unsigned short* __restrict__ Wt,
        const float* __restrict__ dinv, unsigned short* __restrict__ Ybf, int N,
        const int* __restrict__ row, const int* __restrict__ col,
        const float* __restrict__ vals, const int* __restrict__ pos,
        const int* __restrict__ rank, uint2* __restrict__ epack, int E,
        int gemmBlocks) {
    __shared__ unsigned short Wl[N_CH * WT_LD];  // 34 KB

    if ((int)blockIdx.x >= gemmBlocks) {
        // ---- place part ----
        int e0 = (blockIdx.x - gemmBlocks) * 1024 + threadIdx.x;
#pragma unroll
        for (int j = 0; j < 4; ++j) {
            int e = e0 + j * 256;
            if (e < E) {
                int r = row[e];
                int p = pos[r] + rank[e];
                epack[p] = make_uint2((unsigned)col[e], __float_as_uint(vals[e]));
            }
        }
        return;
    }

    // ---- gemm part ----
    const int t = threadIdx.x;
    // stage Wt (16384 ushorts = 2048 short8 chunks, 8 per thread)
    const short8* Wg = (const short8*)Wt;
#pragma unroll
    for (int j = 0; j < 8; ++j) {
        int idx = t + 256 * j;          // chunk id
        int r = idx >> 4, cc = idx & 15;
        *(short8*)(Wl + r * WT_LD + cc * 8) = Wg[idx];
    }
    __syncthreads();

    const int lane = t & 63;
    const int wv = t >> 6;
    const int m = lane & 15;
    const int q = lane >> 4;

#pragma unroll
    for (int i = 0; i < 2; ++i) {
        const int base = (blockIdx.x * 8 + wv * 2 + i) * 16;
        if (base >= N) break;

        // A fragments: 4 k-chunks, 8 fp32 each -> bf16
        short8 a[4];
        const float* xrow = X + (size_t)(base + m) * N_CH + q * 8;
#pragma unroll
        for (int c = 0; c < 4; ++c) {
            f32x4 lo = *(const f32x4*)(xrow + c * 32);
            f32x4 hi = *(const f32x4*)(xrow + c * 32 + 4);
            short8 v;
            v[0] = (short)f2bf(lo[0]); v[1] = (short)f2bf(lo[1]);
            v[2] = (short)f2bf(lo[2]); v[3] = (short)f2bf(lo[3]);
            v[4] = (short)f2bf(hi[0]); v[5] = (short)f2bf(hi[1]);
            v[6] = (short)f2bf(hi[2]); v[7] = (short)f2bf(hi[3]);
            a[c] = v;
        }

        f32x4 acc[8];
#pragma unroll
        for (int tt = 0; tt < 8; ++tt) acc[tt] = (f32x4){0.f, 0.f, 0.f, 0.f};

#pragma unroll
        for (int tt = 0; tt < 8; ++tt) {
            const unsigned short* wrow = Wl + (tt * 16 + m) * WT_LD + q * 8;
#pragma unroll
            for (int c = 0; c < 4; ++c) {
                short8 b = *(const short8*)(wrow + c * 32);
                acc[tt] = __builtin_amdgcn_mfma_f32_16x16x32_bf16(a[c], b, acc[tt], 0, 0, 0);
            }
        }

        float ds[4];
#pragma unroll
        for (int r = 0; r < 4; ++r) ds[r] = dinv[base + q * 4 + r];

#pragma unroll
        for (int tt = 0; tt < 8; ++tt) {
#pragma unroll
            for (int r = 0; r < 4; ++r) {
                Ybf[(size_t)(base + q * 4 + r) * N_CH + tt * 16 + m] = f2bf(acc[tt][r] * ds[r]);
            }
        }
    }
}

// ---- gather: out[n,:] = dinv[n] * sum_e val_e * Y[col_e,:] + bias --------
__global__ __launch_bounds__(256) void gather_kernel(const int* __restrict__ pos,
                                                     const uint2* __restrict__ epack,
                                                     const unsigned short* __restrict__ Ybf,
                                                     const float* __restrict__ dinv,
                                                     const float* __restrict__ bias,
                                                     float* __restrict__ out, int N, int E) {
    unsigned gid = blockIdx.x * 256u + threadIdx.x;
    int n = gid >> 5;
    if (n >= N) return;
    int lane = gid & 31;
    int c = lane * 4;

    int e = pos[n];
    int end = (n + 1 < N) ? pos[n + 1] : E;

    float4 acc = make_float4(0.f, 0.f, 0.f, 0.f);
    for (; e + 4 <= end; e += 4) {
        uint2 p0 = epack[e + 0];
        uint2 p1 = epack[e + 1];
        uint2 p2 = epack[e + 2];
        uint2 p3 = epack[e + 3];
        ushort4v y0 = *(const ushort4v*)(Ybf + (size_t)p0.x * N_CH + c);
        ushort4v y1 = *(const ushort4v*)(Ybf + (size_t)p1.x * N_CH + c);
        ushort4v y2 = *(const ushort4v*)(Ybf + (size_t)p2.x * N_CH + c);
        ushort4v y3 = *(const ushort4v*)(Ybf + (size_t)p3.x * N_CH + c);
        float v0 = __uint_as_float(p0.y);
        float v1 = __uint_as_float(p1.y);
        float v2 = __uint_as_float(p2.y);
        float v3 = __uint_as_float(p3.y);
        acc.x += v0 * bf2f(y0[0]) + v1 * bf2f(y1[0]) + v2 * bf2f(y2[0]) + v3 * bf2f(y3[0]);
        acc.y += v0 * bf2f(y0[1]) + v1 * bf2f(y1[1]) + v2 * bf2f(y2[1]) + v3 * bf2f(y3[1]);
        acc.z += v0 * bf2f(y0[2]) + v1 * bf2f(y1[2]) + v2 * bf2f(y2[2]) + v3 * bf2f(y3[2]);
        acc.w += v0 * bf2f(y0[3]) + v1 * bf2f(y1[3]) + v2 * bf2f(y2[3]) + v3 * bf2f(y3[3]);
    }
    for (; e < end; ++e) {
        uint2 p = epack[e];
        float v = __uint_as_float(p.y);
        ushort4v y = *(const ushort4v*)(Ybf + (size_t)p.x * N_CH + c);
        acc.x += v * bf2f(y[0]);
        acc.y += v * bf2f(y[1]);
        acc.z += v * bf2f(y[2]);
        acc.w += v * bf2f(y[3]);
    }

    float d = dinv[n];
    float4 b = ((const float4*)bias)[lane];
    float4 o;
    o.x = acc.x * d + b.x;
    o.y = acc.y * d + b.y;
    o.z = acc.z * d + b.z;
    o.w = acc.w * d + b.w;
    ((float4*)(out + (size_t)n * N_CH))[lane] = o;
}

extern "C" void kernel_launch(void* const* d_in, const int* in_sizes, int n_in,
                              void* d_out, int out_size, void* d_ws, size_t ws_size,
                              hipStream_t stream) {
    const int*   row  = (const int*)d_in[0];
    const int*   col  = (const int*)d_in[1];
    const float* vals = (const float*)d_in[2];
    const float* X    = (const float*)d_in[3];
    const float* W    = (const float*)d_in[4];
    const float* bias = (const float*)d_in[5];
    float* out = (float*)d_out;

    const int E = in_sizes[0];
    const int N = in_sizes[3] / N_CH;
    const int nb = (N + 255) / 256;

    // workspace layout (8-byte aligned first)
    uint2*          epack = (uint2*)d_ws;                       // E uint2
    unsigned short* Ybf   = (unsigned short*)(epack + E);       // N*128 bf16
    float*          dinv  = (float*)(Ybf + (size_t)N * N_CH);   // N f32
    int*            cnt   = (int*)(dinv + N);                   // N i32
    float*          deg   = (float*)(cnt + N);                  // N f32 (zeroed with cnt)
    int*            pos   = (int*)(deg + N);                    // N i32
    int*            rank  = pos + N;                            // E i32
    int*            bsum  = rank + E;                           // nb i32
    unsigned short* Wt    = (unsigned short*)(bsum + nb);       // 128*128 bf16

    // zero cnt AND deg in one fill (contiguous)
    hipMemsetAsync(cnt, 0, (size_t)N * 2 * sizeof(int), stream);

    const int rankBlocks = (E + 2047) / 2048;                   // 313
    rank_kernel<<<rankBlocks + 64, 256, 0, stream>>>(row, vals, cnt, deg, rank, W, Wt,
                                                     E, rankBlocks);
    scan1_kernel<<<nb, 256, 0, stream>>>(cnt, pos, bsum, N);
    scan3_kernel<<<nb, 256, 0, stream>>>(pos, bsum, deg, dinv, N);

    int tiles = (N + 15) / 16;               // 6250
    int gemmBlocks = (tiles + 7) / 8;        // 8 tiles per block (4 waves x 2)
    int placeBlocks = (E + 1023) / 1024;     // 625
    gemm_place_kernel<<<gemmBlocks + placeBlocks, 256, 0, stream>>>(
        X, Wt, dinv, Ybf, N, row, col, vals, pos, rank, epack, E, gemmBlocks);

    unsigned gth = (unsigned)N * 32u;
    gather_kernel<<<(gth + 255) / 256, 256, 0, stream>>>(pos, epack, Ybf, dinv, bias, out, N, E);
}

// Round 3
// 206.060 us; speedup vs baseline: 1.1503x; 1.1503x over previous
//
#include <hip/hip_runtime.h>
#include <hip/hip_bf16.h>

// GCNConv: out = D * (A @ (D * (X@W))) + bias,  D = rsqrt(rowsum(A)+1)
// N=100000, E=640000, C=128.
// R2: CSR gather replaced atomic scatter (1285->317us).
// R3: bf16 MFMA GEMM (317->301us).
// R4: 1 atomic/edge CSR build, packed uint2 edges, bf16 Y (301->242us).
// R5: MLP unrolls in rank/place/gather (242->230us).
// R6: gemm LDS-staged Wt (latency-bound on global re-fetch), 216us.
// R7: resubmit, 215us. No user dispatch >41us -> launch-count-bound.
// R8: fused 11 launches -> 6, but added 2nd atomic to rank at 377 blocks:
//     rank 65us, Occ 11%, VALU 0.3% -> atomic-LATENCY-bound. 237us (regress).
// R9 (this round): ONE packed u64 atomic/edge (count in hi32 = rank; val in
//     8.24 fixed point in lo32 = deg; max deg ~40 < 2^6 -> no overflow, and
//     quantization 2^-24/edge is noise vs 0.125 tol). 2 edges/thread ->
//     1250 blocks (~20 waves/CU) to hide atomic latency with TLP.

#define N_CH 128
#define WT_LD 136  // padded LDS row stride (ushorts): banks (4m+4q)%32 -> 2-way max
#define FIXS 16777216.0f  // 2^24

typedef __attribute__((ext_vector_type(8))) short short8;
typedef __attribute__((ext_vector_type(4))) float f32x4;
typedef __attribute__((ext_vector_type(4))) unsigned short ushort4v;

__device__ inline unsigned short f2bf(float f) {
    unsigned u = __float_as_uint(f);
    return (unsigned short)((u + 0x7FFFu + ((u >> 16) & 1u)) >> 16);  // RNE
}
__device__ inline float bf2f(unsigned short h) {
    return __uint_as_float(((unsigned)h) << 16);
}

// ---- one u64 atomic/edge: hi32 = running count (old -> rank), lo32 = deg fix8.24
// Blocks [0, rankBlocks): 2 edges/thread. Blocks [rankBlocks, +64): W cvt.
__global__ __launch_bounds__(256) void rank_kernel(const int* __restrict__ row,
                                                   const float* __restrict__ vals,
                                                   unsigned long long* __restrict__ packed,
                                                   int* __restrict__ rank,
                                                   const float* __restrict__ W,
                                                   unsigned short* __restrict__ Wt,
                                                   int E, int rankBlocks) {
    if ((int)blockIdx.x >= rankBlocks) {
        // W convert+transpose: Wt[n][k] = bf16(W[k][n]); 16384 elements
        int i = (blockIdx.x - rankBlocks) * 256 + threadIdx.x;
        int k = i >> 7, n = i & 127;
        Wt[n * N_CH + k] = f2bf(W[k * N_CH + n]);
        return;
    }
    int e0 = blockIdx.x * 512 + threadIdx.x;
#pragma unroll
    for (int j = 0; j < 2; ++j) {
        int e = e0 + j * 256;
        if (e < E) {
            int r = row[e];
            unsigned fx = (unsigned)(vals[e] * FIXS);
            unsigned long long old =
                atomicAdd(&packed[r], (1ULL << 32) | (unsigned long long)fx);
            rank[e] = (int)(old >> 32);
        }
    }
}

// ---- block-local exclusive scan of counts -> pos; block sums -> bsum -----
__global__ __launch_bounds__(256) void scan1_kernel(const unsigned long long* __restrict__ packed,
                                                    int* __restrict__ pos,
                                                    int* __restrict__ bsum, int N) {
    __shared__ int s[256];
    int t = threadIdx.x;
    int i = blockIdx.x * 256 + t;
    int v = (i < N) ? (int)(packed[i] >> 32) : 0;
    s[t] = v;
    __syncthreads();
    for (int off = 1; off < 256; off <<= 1) {
        int x = (t >= off) ? s[t - off] : 0;
        __syncthreads();
        s[t] += x;
        __syncthreads();
    }
    if (i < N) pos[i] = s[t] - v;
    if (t == 255) bsum[blockIdx.x] = s[t];
}

// ---- pos[i] += sum(bsum[0..blk-1]); dinv[i] = rsqrt(deg[i]+1) ------------
// Each block reduces its own bsum prefix (<=391 ints, L2-broadcast).
__global__ __launch_bounds__(256) void scan3_kernel(int* __restrict__ pos,
                                                    const int* __restrict__ bsum,
                                                    const unsigned long long* __restrict__ packed,
                                                    float* __restrict__ dinv, int N) {
    __shared__ int s[256];
    int t = threadIdx.x;
    int b = blockIdx.x;
    int acc = 0;
    for (int j = t; j < b; j += 256) acc += bsum[j];
    s[t] = acc;
    __syncthreads();
    for (int off = 128; off > 0; off >>= 1) {
        if (t < off) s[t] += s[t + off];
        __syncthreads();
    }
    int i = b * 256 + t;
    if (i < N) {
        pos[i] += s[0];
        float deg = (float)(unsigned)(packed[i] & 0xFFFFFFFFull) * (1.0f / FIXS);
        dinv[i] = rsqrtf(deg + 1.0f);
    }
}

// ---- fused dispatch: gemm blocks [0,gemmBlocks) + place blocks after -----
// gemm: Ybf[n,:] = bf16( dinv[n] * (X[n,:] @ W) ), bf16 MFMA.
//   Block = 4 waves, 128 rows. Wt staged in LDS (padded stride -> no bank
//   conflicts); each wave does 2 16-row tiles. C/D: col=lane&15,
//   row=(lane>>4)*4+reg.
// place: epack[pos[r]+rank[e]] = {col,val}; 4 edges/thread, no atomics.
__global__ __launch_bounds__(256) void gemm_place_kernel(
        const float* __restrict__ X, const unsigned short* __restrict__ Wt,
        const float* __restrict__ dinv, unsigned short* __restrict__ Ybf, int N,
        const int* __restrict__ row, const int* __restrict__ col,
        const float* __restrict__ vals, const int* __restrict__ pos,
        const int* __restrict__ rank, uint2* __restrict__ epack, int E,
        int gemmBlocks) {
    __shared__ unsigned short Wl[N_CH * WT_LD];  // 34 KB

    if ((int)blockIdx.x >= gemmBlocks) {
        // ---- place part ----
        int e0 = (blockIdx.x - gemmBlocks) * 1024 + threadIdx.x;
#pragma unroll
        for (int j = 0; j < 4; ++j) {
            int e = e0 + j * 256;
            if (e < E) {
                int r = row[e];
                int p = pos[r] + rank[e];
                epack[p] = make_uint2((unsigned)col[e], __float_as_uint(vals[e]));
            }
        }
        return;
    }

    // ---- gemm part ----
    const int t = threadIdx.x;
    // stage Wt (16384 ushorts = 2048 short8 chunks, 8 per thread)
    const short8* Wg = (const short8*)Wt;
#pragma unroll
    for (int j = 0; j < 8; ++j) {
        int idx = t + 256 * j;          // chunk id
        int r = idx >> 4, cc = idx & 15;
        *(short8*)(Wl + r * WT_LD + cc * 8) = Wg[idx];
    }
    __syncthreads();

    const int lane = t & 63;
    const int wv = t >> 6;
    const int m = lane & 15;
    const int q = lane >> 4;

#pragma unroll
    for (int i = 0; i < 2; ++i) {
        const int base = (blockIdx.x * 8 + wv * 2 + i) * 16;
        if (base >= N) break;

        // A fragments: 4 k-chunks, 8 fp32 each -> bf16
        short8 a[4];
        const float* xrow = X + (size_t)(base + m) * N_CH + q * 8;
#pragma unroll
        for (int c = 0; c < 4; ++c) {
            f32x4 lo = *(const f32x4*)(xrow + c * 32);
            f32x4 hi = *(const f32x4*)(xrow + c * 32 + 4);
            short8 v;
            v[0] = (short)f2bf(lo[0]); v[1] = (short)f2bf(lo[1]);
            v[2] = (short)f2bf(lo[2]); v[3] = (short)f2bf(lo[3]);
            v[4] = (short)f2bf(hi[0]); v[5] = (short)f2bf(hi[1]);
            v[6] = (short)f2bf(hi[2]); v[7] = (short)f2bf(hi[3]);
            a[c] = v;
        }

        f32x4 acc[8];
#pragma unroll
        for (int tt = 0; tt < 8; ++tt) acc[tt] = (f32x4){0.f, 0.f, 0.f, 0.f};

#pragma unroll
        for (int tt = 0; tt < 8; ++tt) {
            const unsigned short* wrow = Wl + (tt * 16 + m) * WT_LD + q * 8;
#pragma unroll
            for (int c = 0; c < 4; ++c) {
                short8 b = *(const short8*)(wrow + c * 32);
                acc[tt] = __builtin_amdgcn_mfma_f32_16x16x32_bf16(a[c], b, acc[tt], 0, 0, 0);
            }
        }

        float ds[4];
#pragma unroll
        for (int r = 0; r < 4; ++r) ds[r] = dinv[base + q * 4 + r];

#pragma unroll
        for (int tt = 0; tt < 8; ++tt) {
#pragma unroll
            for (int r = 0; r < 4; ++r) {
                Ybf[(size_t)(base + q * 4 + r) * N_CH + tt * 16 + m] = f2bf(acc[tt][r] * ds[r]);
            }
        }
    }
}

// ---- gather: out[n,:] = dinv[n] * sum_e val_e * Y[col_e,:] + bias --------
__global__ __launch_bounds__(256) void gather_kernel(const int* __restrict__ pos,
                                                     const uint2* __restrict__ epack,
                                                     const unsigned short* __restrict__ Ybf,
                                                     const float* __restrict__ dinv,
                                                     const float* __restrict__ bias,
                                                     float* __restrict__ out, int N, int E) {
    unsigned gid = blockIdx.x * 256u + threadIdx.x;
    int n = gid >> 5;
    if (n >= N) return;
    int lane = gid & 31;
    int c = lane * 4;

    int e = pos[n];
    int end = (n + 1 < N) ? pos[n + 1] : E;

    float4 acc = make_float4(0.f, 0.f, 0.f, 0.f);
    for (; e + 4 <= end; e += 4) {
        uint2 p0 = epack[e + 0];
        uint2 p1 = epack[e + 1];
        uint2 p2 = epack[e + 2];
        uint2 p3 = epack[e + 3];
        ushort4v y0 = *(const ushort4v*)(Ybf + (size_t)p0.x * N_CH + c);
        ushort4v y1 = *(const ushort4v*)(Ybf + (size_t)p1.x * N_CH + c);
        ushort4v y2 = *(const ushort4v*)(Ybf + (size_t)p2.x * N_CH + c);
        ushort4v y3 = *(const ushort4v*)(Ybf + (size_t)p3.x * N_CH + c);
        float v0 = __uint_as_float(p0.y);
        float v1 = __uint_as_float(p1.y);
        float v2 = __uint_as_float(p2.y);
        float v3 = __uint_as_float(p3.y);
        acc.x += v0 * bf2f(y0[0]) + v1 * bf2f(y1[0]) + v2 * bf2f(y2[0]) + v3 * bf2f(y3[0]);
        acc.y += v0 * bf2f(y0[1]) + v1 * bf2f(y1[1]) + v2 * bf2f(y2[1]) + v3 * bf2f(y3[1]);
        acc.z += v0 * bf2f(y0[2]) + v1 * bf2f(y1[2]) + v2 * bf2f(y2[2]) + v3 * bf2f(y3[2]);
        acc.w += v0 * bf2f(y0[3]) + v1 * bf2f(y1[3]) + v2 * bf2f(y2[3]) + v3 * bf2f(y3[3]);
    }
    for (; e < end; ++e) {
        uint2 p = epack[e];
        float v = __uint_as_float(p.y);
        ushort4v y = *(const ushort4v*)(Ybf + (size_t)p.x * N_CH + c);
        acc.x += v * bf2f(y[0]);
        acc.y += v * bf2f(y[1]);
        acc.z += v * bf2f(y[2]);
        acc.w += v * bf2f(y[3]);
    }

    float d = dinv[n];
    float4 b = ((const float4*)bias)[lane];
    float4 o;
    o.x = acc.x * d + b.x;
    o.y = acc.y * d + b.y;
    o.z = acc.z * d + b.z;
    o.w = acc.w * d + b.w;
    ((float4*)(out + (size_t)n * N_CH))[lane] = o;
}

extern "C" void kernel_launch(void* const* d_in, const int* in_sizes, int n_in,
                              void* d_out, int out_size, void* d_ws, size_t ws_size,
                              hipStream_t stream) {
    const int*   row  = (const int*)d_in[0];
    const int*   col  = (const int*)d_in[1];
    const float* vals = (const float*)d_in[2];
    const float* X    = (const float*)d_in[3];
    const float* W    = (const float*)d_in[4];
    const float* bias = (const float*)d_in[5];
    float* out = (float*)d_out;

    const int E = in_sizes[0];
    const int N = in_sizes[3] / N_CH;
    const int nb = (N + 255) / 256;

    // workspace layout (8-byte aligned first)
    uint2*              epack  = (uint2*)d_ws;                        // E uint2
    unsigned short*     Ybf    = (unsigned short*)(epack + E);        // N*128 bf16
    float*              dinv   = (float*)(Ybf + (size_t)N * N_CH);    // N f32
    unsigned long long* packed = (unsigned long long*)(dinv + N);     // N u64 (zeroed)
    int*                pos    = (int*)(packed + N);                  // N i32
    int*                rank   = pos + N;                             // E i32
    int*                bsum   = rank + E;                            // nb i32
    unsigned short*     Wt     = (unsigned short*)(bsum + nb);        // 128*128 bf16

    hipMemsetAsync(packed, 0, (size_t)N * sizeof(unsigned long long), stream);

    const int rankBlocks = (E + 511) / 512;                           // 1250
    rank_kernel<<<rankBlocks + 64, 256, 0, stream>>>(row, vals, packed, rank, W, Wt,
                                                     E, rankBlocks);
    scan1_kernel<<<nb, 256, 0, stream>>>(packed, pos, bsum, N);
    scan3_kernel<<<nb, 256, 0, stream>>>(pos, bsum, packed, dinv, N);

    int tiles = (N + 15) / 16;               // 6250
    int gemmBlocks = (tiles + 7) / 8;        // 8 tiles per block (4 waves x 2)
    int placeBlocks = (E + 1023) / 1024;     // 625
    gemm_place_kernel<<<gemmBlocks + placeBlocks, 256, 0, stream>>>(
        X, Wt, dinv, Ybf, N, row, col, vals, pos, rank, epack, E, gemmBlocks);

    unsigned gth = (unsigned)N * 32u;
    gather_kernel<<<(gth + 255) / 256, 256, 0, stream>>>(pos, epack, Ybf, dinv, bias, out, N, E);
}

// Round 4
// 204.986 us; speedup vs baseline: 1.1563x; 1.0052x over previous
//
#include <hip/hip_runtime.h>
#include <hip/hip_bf16.h>

// GCNConv: out = D * (A @ (D * (X@W))) + bias,  D = rsqrt(rowsum(A)+1)
// N=100000, E=640000, C=128.
// R2: CSR gather replaced atomic scatter (1285->317us).
// R3: bf16 MFMA GEMM (317->301us).
// R4: 1 atomic/edge CSR build, packed uint2 edges, bf16 Y (301->242us).
// R5: MLP unrolls in rank/place/gather (242->230us).
// R6: gemm LDS-staged Wt (latency-bound on global re-fetch), 216us.
// R7: resubmit, 215us. No user dispatch >41us -> launch-count-bound.
// R8: fused 11 launches -> 6; 2nd atomic in rank at low TLP regressed (237us).
// R9: ONE packed u64 atomic/edge (rank hi32 / deg fix8.24 lo32), 1250 blocks.
//     206us. gemm_place now top (42us, MfmaUtil 2.5%, all pipes idle ->
//     latency-bound on epilogue: 32x 2B stores + 4 scattered dinv loads/lane).
// R10 (this round): SWap MFMA operands (mfma(Wfrag,Xfrag) transposes D since
//     A/B lane layouts are identical). Lane now owns ONE X-row: 8x 8B packed
//     stores per tile (4x fewer), 1 dinv load (4x fewer). Fragments unchanged.

#define N_CH 128
#define WT_LD 136  // padded LDS row stride (ushorts): banks (4m+4q)%32 -> 2-way max
#define FIXS 16777216.0f  // 2^24

typedef __attribute__((ext_vector_type(8))) short short8;
typedef __attribute__((ext_vector_type(4))) float f32x4;
typedef __attribute__((ext_vector_type(4))) unsigned short ushort4v;

__device__ inline unsigned short f2bf(float f) {
    unsigned u = __float_as_uint(f);
    return (unsigned short)((u + 0x7FFFu + ((u >> 16) & 1u)) >> 16);  // RNE
}
__device__ inline float bf2f(unsigned short h) {
    return __uint_as_float(((unsigned)h) << 16);
}

// ---- one u64 atomic/edge: hi32 = running count (old -> rank), lo32 = deg fix8.24
// Blocks [0, rankBlocks): 2 edges/thread. Blocks [rankBlocks, +64): W cvt.
__global__ __launch_bounds__(256) void rank_kernel(const int* __restrict__ row,
                                                   const float* __restrict__ vals,
                                                   unsigned long long* __restrict__ packed,
                                                   int* __restrict__ rank,
                                                   const float* __restrict__ W,
                                                   unsigned short* __restrict__ Wt,
                                                   int E, int rankBlocks) {
    if ((int)blockIdx.x >= rankBlocks) {
        // W convert+transpose: Wt[n][k] = bf16(W[k][n]); 16384 elements
        int i = (blockIdx.x - rankBlocks) * 256 + threadIdx.x;
        int k = i >> 7, n = i & 127;
        Wt[n * N_CH + k] = f2bf(W[k * N_CH + n]);
        return;
    }
    int e0 = blockIdx.x * 512 + threadIdx.x;
#pragma unroll
    for (int j = 0; j < 2; ++j) {
        int e = e0 + j * 256;
        if (e < E) {
            int r = row[e];
            unsigned fx = (unsigned)(vals[e] * FIXS);
            unsigned long long old =
                atomicAdd(&packed[r], (1ULL << 32) | (unsigned long long)fx);
            rank[e] = (int)(old >> 32);
        }
    }
}

// ---- block-local exclusive scan of counts -> pos; block sums -> bsum -----
__global__ __launch_bounds__(256) void scan1_kernel(const unsigned long long* __restrict__ packed,
                                                    int* __restrict__ pos,
                                                    int* __restrict__ bsum, int N) {
    __shared__ int s[256];
    int t = threadIdx.x;
    int i = blockIdx.x * 256 + t;
    int v = (i < N) ? (int)(packed[i] >> 32) : 0;
    s[t] = v;
    __syncthreads();
    for (int off = 1; off < 256; off <<= 1) {
        int x = (t >= off) ? s[t - off] : 0;
        __syncthreads();
        s[t] += x;
        __syncthreads();
    }
    if (i < N) pos[i] = s[t] - v;
    if (t == 255) bsum[blockIdx.x] = s[t];
}

// ---- pos[i] += sum(bsum[0..blk-1]); dinv[i] = rsqrt(deg[i]+1) ------------
// Each block reduces its own bsum prefix (<=391 ints, L2-broadcast).
__global__ __launch_bounds__(256) void scan3_kernel(int* __restrict__ pos,
                                                    const int* __restrict__ bsum,
                                                    const unsigned long long* __restrict__ packed,
                                                    float* __restrict__ dinv, int N) {
    __shared__ int s[256];
    int t = threadIdx.x;
    int b = blockIdx.x;
    int acc = 0;
    for (int j = t; j < b; j += 256) acc += bsum[j];
    s[t] = acc;
    __syncthreads();
    for (int off = 128; off > 0; off >>= 1) {
        if (t < off) s[t] += s[t + off];
        __syncthreads();
    }
    int i = b * 256 + t;
    if (i < N) {
        pos[i] += s[0];
        float deg = (float)(unsigned)(packed[i] & 0xFFFFFFFFull) * (1.0f / FIXS);
        dinv[i] = rsqrtf(deg + 1.0f);
    }
}

// ---- fused dispatch: gemm blocks [0,gemmBlocks) + place blocks after -----
// gemm: Ybf[n,:] = bf16( dinv[n] * (X[n,:] @ W) ), bf16 MFMA, SWAPPED
//   operands: mfma(Wfrag, Xfrag) -> D[n_chunk][x_row]: lane&15 = X row,
//   (lane>>4)*4+reg = col within 16-col chunk tt. Lane owns one X row ->
//   packed 8B stores, single dinv load.
// place: epack[pos[r]+rank[e]] = {col,val}; 4 edges/thread, no atomics.
__global__ __launch_bounds__(256) void gemm_place_kernel(
        const float* __restrict__ X, const unsigned short* __restrict__ Wt,
        const float* __restrict__ dinv, unsigned short* __restrict__ Ybf, int N,
        const int* __restrict__ row, const int* __restrict__ col,
        const float* __restrict__ vals, const int* __restrict__ pos,
        const int* __restrict__ rank, uint2* __restrict__ epack, int E,
        int gemmBlocks) {
    __shared__ unsigned short Wl[N_CH * WT_LD];  // 34 KB

    if ((int)blockIdx.x >= gemmBlocks) {
        // ---- place part ----
        int e0 = (blockIdx.x - gemmBlocks) * 1024 + threadIdx.x;
#pragma unroll
        for (int j = 0; j < 4; ++j) {
            int e = e0 + j * 256;
            if (e < E) {
                int r = row[e];
                int p = pos[r] + rank[e];
                epack[p] = make_uint2((unsigned)col[e], __float_as_uint(vals[e]));
            }
        }
        return;
    }

    // ---- gemm part ----
    const int t = threadIdx.x;
    // stage Wt (16384 ushorts = 2048 short8 chunks, 8 per thread)
    const short8* Wg = (const short8*)Wt;
#pragma unroll
    for (int j = 0; j < 8; ++j) {
        int idx = t + 256 * j;          // chunk id
        int r = idx >> 4, cc = idx & 15;
        *(short8*)(Wl + r * WT_LD + cc * 8) = Wg[idx];
    }
    __syncthreads();

    const int lane = t & 63;
    const int wv = t >> 6;
    const int m = lane & 15;   // X row within tile AND W-fragment row select
    const int q = lane >> 4;   // k-subchunk select; also output col group (q*4+reg)

#pragma unroll
    for (int i = 0; i < 2; ++i) {
        const int base = (blockIdx.x * 8 + wv * 2 + i) * 16;
        if (base >= N) break;

        // A fragments (X rows): 4 k-chunks, 8 fp32 each -> bf16
        short8 a[4];
        const float* xrow = X + (size_t)(base + m) * N_CH + q * 8;
#pragma unroll
        for (int c = 0; c < 4; ++c) {
            f32x4 lo = *(const f32x4*)(xrow + c * 32);
            f32x4 hi = *(const f32x4*)(xrow + c * 32 + 4);
            short8 v;
            v[0] = (short)f2bf(lo[0]); v[1] = (short)f2bf(lo[1]);
            v[2] = (short)f2bf(lo[2]); v[3] = (short)f2bf(lo[3]);
            v[4] = (short)f2bf(hi[0]); v[5] = (short)f2bf(hi[1]);
            v[6] = (short)f2bf(hi[2]); v[7] = (short)f2bf(hi[3]);
            a[c] = v;
        }

        f32x4 acc[8];
#pragma unroll
        for (int tt = 0; tt < 8; ++tt) acc[tt] = (f32x4){0.f, 0.f, 0.f, 0.f};

#pragma unroll
        for (int tt = 0; tt < 8; ++tt) {
            const unsigned short* wrow = Wl + (tt * 16 + m) * WT_LD + q * 8;
#pragma unroll
            for (int c = 0; c < 4; ++c) {
                short8 b = *(const short8*)(wrow + c * 32);
                // SWAPPED: D[i=W-row][j=X-row] -> lane&15 = X row (j),
                // (lane>>4)*4+reg = n within chunk tt (i).
                acc[tt] = __builtin_amdgcn_mfma_f32_16x16x32_bf16(b, a[c], acc[tt], 0, 0, 0);
            }
        }

        const float d = dinv[base + m];  // one row per lane now
        unsigned short* yrow = Ybf + (size_t)(base + m) * N_CH;
#pragma unroll
        for (int tt = 0; tt < 8; ++tt) {
            unsigned lo = (unsigned)f2bf(acc[tt][0] * d) |
                          ((unsigned)f2bf(acc[tt][1] * d) << 16);
            unsigned hi = (unsigned)f2bf(acc[tt][2] * d) |
                          ((unsigned)f2bf(acc[tt][3] * d) << 16);
            *(uint2*)(yrow + tt * 16 + q * 4) = make_uint2(lo, hi);
        }
    }
}

// ---- gather: out[n,:] = dinv[n] * sum_e val_e * Y[col_e,:] + bias --------
__global__ __launch_bounds__(256) void gather_kernel(const int* __restrict__ pos,
                                                     const uint2* __restrict__ epack,
                                                     const unsigned short* __restrict__ Ybf,
                                                     const float* __restrict__ dinv,
                                                     const float* __restrict__ bias,
                                                     float* __restrict__ out, int N, int E) {
    unsigned gid = blockIdx.x * 256u + threadIdx.x;
    int n = gid >> 5;
    if (n >= N) return;
    int lane = gid & 31;
    int c = lane * 4;

    int e = pos[n];
    int end = (n + 1 < N) ? pos[n + 1] : E;

    float4 acc = make_float4(0.f, 0.f, 0.f, 0.f);
    for (; e + 4 <= end; e += 4) {
        uint2 p0 = epack[e + 0];
        uint2 p1 = epack[e + 1];
        uint2 p2 = epack[e + 2];
        uint2 p3 = epack[e + 3];
        ushort4v y0 = *(const ushort4v*)(Ybf + (size_t)p0.x * N_CH + c);
        ushort4v y1 = *(const ushort4v*)(Ybf + (size_t)p1.x * N_CH + c);
        ushort4v y2 = *(const ushort4v*)(Ybf + (size_t)p2.x * N_CH + c);
        ushort4v y3 = *(const ushort4v*)(Ybf + (size_t)p3.x * N_CH + c);
        float v0 = __uint_as_float(p0.y);
        float v1 = __uint_as_float(p1.y);
        float v2 = __uint_as_float(p2.y);
        float v3 = __uint_as_float(p3.y);
        acc.x += v0 * bf2f(y0[0]) + v1 * bf2f(y1[0]) + v2 * bf2f(y2[0]) + v3 * bf2f(y3[0]);
        acc.y += v0 * bf2f(y0[1]) + v1 * bf2f(y1[1]) + v2 * bf2f(y2[1]) + v3 * bf2f(y3[1]);
        acc.z += v0 * bf2f(y0[2]) + v1 * bf2f(y1[2]) + v2 * bf2f(y2[2]) + v3 * bf2f(y3[2]);
        acc.w += v0 * bf2f(y0[3]) + v1 * bf2f(y1[3]) + v2 * bf2f(y2[3]) + v3 * bf2f(y3[3]);
    }
    for (; e < end; ++e) {
        uint2 p = epack[e];
        float v = __uint_as_float(p.y);
        ushort4v y = *(const ushort4v*)(Ybf + (size_t)p.x * N_CH + c);
        acc.x += v * bf2f(y[0]);
        acc.y += v * bf2f(y[1]);
        acc.z += v * bf2f(y[2]);
        acc.w += v * bf2f(y[3]);
    }

    float d = dinv[n];
    float4 b = ((const float4*)bias)[lane];
    float4 o;
    o.x = acc.x * d + b.x;
    o.y = acc.y * d + b.y;
    o.z = acc.z * d + b.z;
    o.w = acc.w * d + b.w;
    ((float4*)(out + (size_t)n * N_CH))[lane] = o;
}

extern "C" void kernel_launch(void* const* d_in, const int* in_sizes, int n_in,
                              void* d_out, int out_size, void* d_ws, size_t ws_size,
                              hipStream_t stream) {
    const int*   row  = (const int*)d_in[0];
    const int*   col  = (const int*)d_in[1];
    const float* vals = (const float*)d_in[2];
    const float* X    = (const float*)d_in[3];
    const float* W    = (const float*)d_in[4];
    const float* bias = (const float*)d_in[5];
    float* out = (float*)d_out;

    const int E = in_sizes[0];
    const int N = in_sizes[3] / N_CH;
    const int nb = (N + 255) / 256;

    // workspace layout (8-byte aligned first)
    uint2*              epack  = (uint2*)d_ws;                        // E uint2
    unsigned short*     Ybf    = (unsigned short*)(epack + E);        // N*128 bf16
    float*              dinv   = (float*)(Ybf + (size_t)N * N_CH);    // N f32
    unsigned long long* packed = (unsigned long long*)(dinv + N);     // N u64 (zeroed)
    int*                pos    = (int*)(packed + N);                  // N i32
    int*                rank   = pos + N;                             // E i32
    int*                bsum   = rank + E;                            // nb i32
    unsigned short*     Wt     = (unsigned short*)(bsum + nb);        // 128*128 bf16

    hipMemsetAsync(packed, 0, (size_t)N * sizeof(unsigned long long), stream);

    const int rankBlocks = (E + 511) / 512;                           // 1250
    rank_kernel<<<rankBlocks + 64, 256, 0, stream>>>(row, vals, packed, rank, W, Wt,
                                                     E, rankBlocks);
    scan1_kernel<<<nb, 256, 0, stream>>>(packed, pos, bsum, N);
    scan3_kernel<<<nb, 256, 0, stream>>>(pos, bsum, packed, dinv, N);

    int tiles = (N + 15) / 16;               // 6250
    int gemmBlocks = (tiles + 7) / 8;        // 8 tiles per block (4 waves x 2)
    int placeBlocks = (E + 1023) / 1024;     // 625
    gemm_place_kernel<<<gemmBlocks + placeBlocks, 256, 0, stream>>>(
        X, Wt, dinv, Ybf, N, row, col, vals, pos, rank, epack, E, gemmBlocks);

    unsigned gth = (unsigned)N * 32u;
    gather_kernel<<<(gth + 255) / 256, 256, 0, stream>>>(pos, epack, Ybf, dinv, bias, out, N, E);
}

// Round 5
// 202.758 us; speedup vs baseline: 1.1690x; 1.0110x over previous
//
#include <hip/hip_runtime.h>
#include <hip/hip_bf16.h>

// GCNConv: out = D * (A @ (D * (X@W))) + bias,  D = rsqrt(rowsum(A)+1)
// N=100000, E=640000, C=128.
// R2..R6: 1285 -> 216us (CSR gather, MFMA, packed edges, LDS-staged Wt).
// R7: resubmit, 215us. Launch-count-bound.
// R8: fused 11 launches -> 6; 2nd atomic in rank regressed (237us).
// R9: ONE packed u64 atomic/edge + TLP in rank. 206us.
// R10: swapped-operand MFMA epilogue (packed 8B stores). 205us, gemm_place
//      46us NOT store-bound: all pipes idle, wave lifetime = serial cold
//      latency (stage Wt -> X loads -> compute) x 1400 short-lived blocks.
// R11 (this round): PERSISTENT gemm: 512 blocks (2/CU), grid-stride over
//      tiles (3-4/wave), Wt staged once/block, X of next tile prefetched
//      into regs under current tile's cvt+MFMA. Place part unchanged.

#define N_CH 128
#define WT_LD 136  // padded LDS row stride (ushorts): banks (4m+4q)%32 -> 2-way max
#define FIXS 16777216.0f  // 2^24

typedef __attribute__((ext_vector_type(8))) short short8;
typedef __attribute__((ext_vector_type(4))) float f32x4;
typedef __attribute__((ext_vector_type(4))) unsigned short ushort4v;

__device__ inline unsigned short f2bf(float f) {
    unsigned u = __float_as_uint(f);
    return (unsigned short)((u + 0x7FFFu + ((u >> 16) & 1u)) >> 16);  // RNE
}
__device__ inline float bf2f(unsigned short h) {
    return __uint_as_float(((unsigned)h) << 16);
}

// ---- one u64 atomic/edge: hi32 = running count (old -> rank), lo32 = deg fix8.24
// Blocks [0, rankBlocks): 2 edges/thread. Blocks [rankBlocks, +64): W cvt.
__global__ __launch_bounds__(256) void rank_kernel(const int* __restrict__ row,
                                                   const float* __restrict__ vals,
                                                   unsigned long long* __restrict__ packed,
                                                   int* __restrict__ rank,
                                                   const float* __restrict__ W,
                                                   unsigned short* __restrict__ Wt,
                                                   int E, int rankBlocks) {
    if ((int)blockIdx.x >= rankBlocks) {
        // W convert+transpose: Wt[n][k] = bf16(W[k][n]); 16384 elements
        int i = (blockIdx.x - rankBlocks) * 256 + threadIdx.x;
        int k = i >> 7, n = i & 127;
        Wt[n * N_CH + k] = f2bf(W[k * N_CH + n]);
        return;
    }
    int e0 = blockIdx.x * 512 + threadIdx.x;
#pragma unroll
    for (int j = 0; j < 2; ++j) {
        int e = e0 + j * 256;
        if (e < E) {
            int r = row[e];
            unsigned fx = (unsigned)(vals[e] * FIXS);
            unsigned long long old =
                atomicAdd(&packed[r], (1ULL << 32) | (unsigned long long)fx);
            rank[e] = (int)(old >> 32);
        }
    }
}

// ---- block-local exclusive scan of counts -> pos; block sums -> bsum -----
__global__ __launch_bounds__(256) void scan1_kernel(const unsigned long long* __restrict__ packed,
                                                    int* __restrict__ pos,
                                                    int* __restrict__ bsum, int N) {
    __shared__ int s[256];
    int t = threadIdx.x;
    int i = blockIdx.x * 256 + t;
    int v = (i < N) ? (int)(packed[i] >> 32) : 0;
    s[t] = v;
    __syncthreads();
    for (int off = 1; off < 256; off <<= 1) {
        int x = (t >= off) ? s[t - off] : 0;
        __syncthreads();
        s[t] += x;
        __syncthreads();
    }
    if (i < N) pos[i] = s[t] - v;
    if (t == 255) bsum[blockIdx.x] = s[t];
}

// ---- pos[i] += sum(bsum[0..blk-1]); dinv[i] = rsqrt(deg[i]+1) ------------
__global__ __launch_bounds__(256) void scan3_kernel(int* __restrict__ pos,
                                                    const int* __restrict__ bsum,
                                                    const unsigned long long* __restrict__ packed,
                                                    float* __restrict__ dinv, int N) {
    __shared__ int s[256];
    int t = threadIdx.x;
    int b = blockIdx.x;
    int acc = 0;
    for (int j = t; j < b; j += 256) acc += bsum[j];
    s[t] = acc;
    __syncthreads();
    for (int off = 128; off > 0; off >>= 1) {
        if (t < off) s[t] += s[t + off];
        __syncthreads();
    }
    int i = b * 256 + t;
    if (i < N) {
        pos[i] += s[0];
        float deg = (float)(unsigned)(packed[i] & 0xFFFFFFFFull) * (1.0f / FIXS);
        dinv[i] = rsqrtf(deg + 1.0f);
    }
}

// ---- fused dispatch: persistent gemm blocks [0,gemmBlocks) + place -------
// gemm: Ybf[n,:] = bf16( dinv[n] * (X[n,:] @ W) ), swapped-operand MFMA
//   (lane&15 = X row, (lane>>4)*4+reg = out col in chunk tt). Each wave
//   grid-strides over 16-row tiles; next tile's X prefetched into regs.
// place: epack[pos[r]+rank[e]] = {col,val}; 4 edges/thread, no atomics.
__global__ __launch_bounds__(256) void gemm_place_kernel(
        const float* __restrict__ X, const unsigned short* __restrict__ Wt,
        const float* __restrict__ dinv, unsigned short* __restrict__ Ybf, int N,
        const int* __restrict__ row, const int* __restrict__ col,
        const float* __restrict__ vals, const int* __restrict__ pos,
        const int* __restrict__ rank, uint2* __restrict__ epack, int E,
        int gemmBlocks) {
    __shared__ unsigned short Wl[N_CH * WT_LD];  // 34 KB

    if ((int)blockIdx.x >= gemmBlocks) {
        // ---- place part ----
        int e0 = (blockIdx.x - gemmBlocks) * 1024 + threadIdx.x;
#pragma unroll
        for (int j = 0; j < 4; ++j) {
            int e = e0 + j * 256;
            if (e < E) {
                int r = row[e];
                int p = pos[r] + rank[e];
                epack[p] = make_uint2((unsigned)col[e], __float_as_uint(vals[e]));
            }
        }
        return;
    }

    // ---- gemm part ----
    const int t = threadIdx.x;
    // stage Wt once per block (16384 ushorts = 2048 short8 chunks)
    const short8* Wg = (const short8*)Wt;
#pragma unroll
    for (int j = 0; j < 8; ++j) {
        int idx = t + 256 * j;          // chunk id
        int r = idx >> 4, cc = idx & 15;
        *(short8*)(Wl + r * WT_LD + cc * 8) = Wg[idx];
    }
    __syncthreads();

    const int lane = t & 63;
    const int wv = t >> 6;
    const int m = lane & 15;   // X row within tile; W-fragment row select
    const int q = lane >> 4;   // k-subchunk; also output col group (q*4+reg)

    const int tiles = (N + 15) / 16;
    const int totalWaves = gemmBlocks * 4;
    int tile = blockIdx.x * 4 + wv;
    if (tile >= tiles) return;

    // prologue: load first tile's X rows (raw f32)
    f32x4 pl[4], ph[4];
    {
        int rr = tile * 16 + m;
        if (rr >= N) rr = N - 1;
        const float* xr = X + (size_t)rr * N_CH + q * 8;
#pragma unroll
        for (int c = 0; c < 4; ++c) {
            pl[c] = *(const f32x4*)(xr + c * 32);
            ph[c] = *(const f32x4*)(xr + c * 32 + 4);
        }
    }

    while (true) {
        const int next = tile + totalWaves;
        const bool hasNext = next < tiles;

        // issue next tile's X loads early (hide under cvt+MFMA below)
        f32x4 ql[4], qh[4];
        if (hasNext) {
            int rr2 = next * 16 + m;
            if (rr2 >= N) rr2 = N - 1;
            const float* xr2 = X + (size_t)rr2 * N_CH + q * 8;
#pragma unroll
            for (int c = 0; c < 4; ++c) {
                ql[c] = *(const f32x4*)(xr2 + c * 32);
                qh[c] = *(const f32x4*)(xr2 + c * 32 + 4);
            }
        }

        // cvt current tile f32 -> bf16 fragments
        short8 a[4];
#pragma unroll
        for (int c = 0; c < 4; ++c) {
            short8 v;
            v[0] = (short)f2bf(pl[c][0]); v[1] = (short)f2bf(pl[c][1]);
            v[2] = (short)f2bf(pl[c][2]); v[3] = (short)f2bf(pl[c][3]);
            v[4] = (short)f2bf(ph[c][0]); v[5] = (short)f2bf(ph[c][1]);
            v[6] = (short)f2bf(ph[c][2]); v[7] = (short)f2bf(ph[c][3]);
            a[c] = v;
        }

        f32x4 acc[8];
#pragma unroll
        for (int tt = 0; tt < 8; ++tt) acc[tt] = (f32x4){0.f, 0.f, 0.f, 0.f};

#pragma unroll
        for (int tt = 0; tt < 8; ++tt) {
            const unsigned short* wrow = Wl + (tt * 16 + m) * WT_LD + q * 8;
#pragma unroll
            for (int c = 0; c < 4; ++c) {
                short8 b = *(const short8*)(wrow + c * 32);
                // swapped: D[i=W-row][j=X-row]
                acc[tt] = __builtin_amdgcn_mfma_f32_16x16x32_bf16(b, a[c], acc[tt], 0, 0, 0);
            }
        }

        const int rr = tile * 16 + m;
        if (rr < N) {
            const float d = dinv[rr];
            unsigned short* yrow = Ybf + (size_t)rr * N_CH;
#pragma unroll
            for (int tt = 0; tt < 8; ++tt) {
                unsigned lo = (unsigned)f2bf(acc[tt][0] * d) |
                              ((unsigned)f2bf(acc[tt][1] * d) << 16);
                unsigned hi = (unsigned)f2bf(acc[tt][2] * d) |
                              ((unsigned)f2bf(acc[tt][3] * d) << 16);
                *(uint2*)(yrow + tt * 16 + q * 4) = make_uint2(lo, hi);
            }
        }

        if (!hasNext) break;
#pragma unroll
        for (int c = 0; c < 4; ++c) { pl[c] = ql[c]; ph[c] = qh[c]; }
        tile = next;
    }
}

// ---- gather: out[n,:] = dinv[n] * sum_e val_e * Y[col_e,:] + bias --------
__global__ __launch_bounds__(256) void gather_kernel(const int* __restrict__ pos,
                                                     const uint2* __restrict__ epack,
                                                     const unsigned short* __restrict__ Ybf,
                                                     const float* __restrict__ dinv,
                                                     const float* __restrict__ bias,
                                                     float* __restrict__ out, int N, int E) {
    unsigned gid = blockIdx.x * 256u + threadIdx.x;
    int n = gid >> 5;
    if (n >= N) return;
    int lane = gid & 31;
    int c = lane * 4;

    int e = pos[n];
    int end = (n + 1 < N) ? pos[n + 1] : E;

    float4 acc = make_float4(0.f, 0.f, 0.f, 0.f);
    for (; e + 4 <= end; e += 4) {
        uint2 p0 = epack[e + 0];
        uint2 p1 = epack[e + 1];
        uint2 p2 = epack[e + 2];
        uint2 p3 = epack[e + 3];
        ushort4v y0 = *(const ushort4v*)(Ybf + (size_t)p0.x * N_CH + c);
        ushort4v y1 = *(const ushort4v*)(Ybf + (size_t)p1.x * N_CH + c);
        ushort4v y2 = *(const ushort4v*)(Ybf + (size_t)p2.x * N_CH + c);
        ushort4v y3 = *(const ushort4v*)(Ybf + (size_t)p3.x * N_CH + c);
        float v0 = __uint_as_float(p0.y);
        float v1 = __uint_as_float(p1.y);
        float v2 = __uint_as_float(p2.y);
        float v3 = __uint_as_float(p3.y);
        acc.x += v0 * bf2f(y0[0]) + v1 * bf2f(y1[0]) + v2 * bf2f(y2[0]) + v3 * bf2f(y3[0]);
        acc.y += v0 * bf2f(y0[1]) + v1 * bf2f(y1[1]) + v2 * bf2f(y2[1]) + v3 * bf2f(y3[1]);
        acc.z += v0 * bf2f(y0[2]) + v1 * bf2f(y1[2]) + v2 * bf2f(y2[2]) + v3 * bf2f(y3[2]);
        acc.w += v0 * bf2f(y0[3]) + v1 * bf2f(y1[3]) + v2 * bf2f(y2[3]) + v3 * bf2f(y3[3]);
    }
    for (; e < end; ++e) {
        uint2 p = epack[e];
        float v = __uint_as_float(p.y);
        ushort4v y = *(const ushort4v*)(Ybf + (size_t)p.x * N_CH + c);
        acc.x += v * bf2f(y[0]);
        acc.y += v * bf2f(y[1]);
        acc.z += v * bf2f(y[2]);
        acc.w += v * bf2f(y[3]);
    }

    float d = dinv[n];
    float4 b = ((const float4*)bias)[lane];
    float4 o;
    o.x = acc.x * d + b.x;
    o.y = acc.y * d + b.y;
    o.z = acc.z * d + b.z;
    o.w = acc.w * d + b.w;
    ((float4*)(out + (size_t)n * N_CH))[lane] = o;
}

extern "C" void kernel_launch(void* const* d_in, const int* in_sizes, int n_in,
                              void* d_out, int out_size, void* d_ws, size_t ws_size,
                              hipStream_t stream) {
    const int*   row  = (const int*)d_in[0];
    const int*   col  = (const int*)d_in[1];
    const float* vals = (const float*)d_in[2];
    const float* X    = (const float*)d_in[3];
    const float* W    = (const float*)d_in[4];
    const float* bias = (const float*)d_in[5];
    float* out = (float*)d_out;

    const int E = in_sizes[0];
    const int N = in_sizes[3] / N_CH;
    const int nb = (N + 255) / 256;

    // workspace layout (8-byte aligned first)
    uint2*              epack  = (uint2*)d_ws;                        // E uint2
    unsigned short*     Ybf    = (unsigned short*)(epack + E);        // N*128 bf16
    float*              dinv   = (float*)(Ybf + (size_t)N * N_CH);    // N f32
    unsigned long long* packed = (unsigned long long*)(dinv + N);     // N u64 (zeroed)
    int*                pos    = (int*)(packed + N);                  // N i32
    int*                rank   = pos + N;                             // E i32
    int*                bsum   = rank + E;                            // nb i32
    unsigned short*     Wt     = (unsigned short*)(bsum + nb);        // 128*128 bf16

    hipMemsetAsync(packed, 0, (size_t)N * sizeof(unsigned long long), stream);

    const int rankBlocks = (E + 511) / 512;                           // 1250
    rank_kernel<<<rankBlocks + 64, 256, 0, stream>>>(row, vals, packed, rank, W, Wt,
                                                     E, rankBlocks);
    scan1_kernel<<<nb, 256, 0, stream>>>(packed, pos, bsum, N);
    scan3_kernel<<<nb, 256, 0, stream>>>(pos, bsum, packed, dinv, N);

    const int gemmBlocks = 512;              // persistent: 2 blocks/CU (LDS cap 4)
    int placeBlocks = (E + 1023) / 1024;     // 625
    gemm_place_kernel<<<gemmBlocks + placeBlocks, 256, 0, stream>>>(
        X, Wt, dinv, Ybf, N, row, col, vals, pos, rank, epack, E, gemmBlocks);

    unsigned gth = (unsigned)N * 32u;
    gather_kernel<<<(gth + 255) / 256, 256, 0, stream>>>(pos, epack, Ybf, dinv, bias, out, N, E);
}